// Round 8
// baseline (176.171 us; speedup 1.0000x reference)
//
#include <hip/hip_runtime.h>

#define Bn 2
#define Nn 4096
#define Cn 256
#define Kn 64
#define BK (Bn * Kn)
#define NSEG 8                 // eighths of N per box
#define SEGN (Nn / NSEG)       // 512 points per block
#define NB1 (BK * NSEG)        // 1024 blocks
#define W1T 4                  // waves per block
#define PAD1 (7 * W1T)         // gather batch over-read padding

__device__ __forceinline__ float4 max4(float4 a, float4 b) {
    return make_float4(fmaxf(a.x, b.x), fmaxf(a.y, b.y),
                       fmaxf(a.z, b.z), fmaxf(a.w, b.w));
}

// One kernel: (box, eighth) scan -> ballot compact -> wave-row float4
// gather-max -> partial write -> device-scope release; the LAST block of
// each box (per-box counter) acquires and runs that box's 2-layer MLP,
// overlapping other boxes' gathers. No second launch, no global barrier.
__global__ __launch_bounds__(256) void pool_seg_mlp_kernel(
    const float* __restrict__ points,      // (B,N,3)
    const float* __restrict__ feats,       // (B,N,C)
    const float* __restrict__ proposals,   // (B,K,7)
    const float* __restrict__ W1,          // (C,256)
    const float* __restrict__ b1,
    const float* __restrict__ W2,          // (256,256)
    const float* __restrict__ b2,
    float* __restrict__ out,               // (B,K,256)
    float* __restrict__ partial,           // (NB1, 256): -inf when empty
    unsigned* __restrict__ counters)       // (BK) zeroed by memset
{
    const int blk  = blockIdx.x;
    const int bk   = blk >> 3;             // box 0..127
    const int seg  = blk & 7;              // eighth 0..7
    const int b    = bk / Kn;
    const int tid  = threadIdx.x;
    const int w    = tid >> 6;             // wave 0..3
    const int lane = tid & 63;

    __shared__ int   s_idx[SEGN + PAD1];   // 2.2 KB
    __shared__ int   s_count;
    __shared__ float s_part[W1T][Cn];      // 4 KB
    __shared__ float s_vec[Cn];            // 1 KB (pooled vec / h)
    __shared__ float s_h[Cn];              // 1 KB
    __shared__ int   s_done;

    // ---- box bounds ----
    const float* prop = proposals + (size_t)bk * 7;
    const float cx = prop[0], cy = prop[1], cz = prop[2];
    const float hx = prop[3] * 0.5f, hy = prop[4] * 0.5f, hz = prop[5] * 0.5f;
    const float lox = cx - hx, loy = cy - hy, loz = cz - hz;
    const float hix = cx + hx, hiy = cy + hy, hiz = cz + hz;

    if (tid == 0) s_count = 0;
    __syncthreads();

    // ---- phase 1: scan this eighth's 512 points. Threads 0..127 own 4
    // points each via 3 float4 loads; wave-aggregated ballot compaction.
    if (tid < 128) {
        const int n0 = seg * SEGN + 4 * tid;
        const float4* pv = (const float4*)(points + (size_t)b * Nn * 3
                                           + (size_t)seg * SEGN * 3);
        const float4 q0 = pv[3 * tid + 0];   // x0 y0 z0 x1
        const float4 q1 = pv[3 * tid + 1];   // y1 z1 x2 y2
        const float4 q2 = pv[3 * tid + 2];   // z2 x3 y3 z3

        const bool in0 = (q0.x > lox) & (q0.x < hix) &
                         (q0.y > loy) & (q0.y < hiy) &
                         (q0.z > loz) & (q0.z < hiz);
        const bool in1 = (q0.w > lox) & (q0.w < hix) &
                         (q1.x > loy) & (q1.x < hiy) &
                         (q1.y > loz) & (q1.y < hiz);
        const bool in2 = (q1.z > lox) & (q1.z < hix) &
                         (q1.w > loy) & (q1.w < hiy) &
                         (q2.x > loz) & (q2.x < hiz);
        const bool in3 = (q2.y > lox) & (q2.y < hix) &
                         (q2.z > loy) & (q2.z < hiy) &
                         (q2.w > loz) & (q2.w < hiz);

        const unsigned long long m0 = __ballot(in0);
        const unsigned long long m1 = __ballot(in1);
        const unsigned long long m2 = __ballot(in2);
        const unsigned long long m3 = __ballot(in3);
        const int c0 = __popcll(m0), c1 = __popcll(m1);
        const int c2 = __popcll(m2), c3 = __popcll(m3);

        int base = 0;
        if (lane == 0) base = atomicAdd(&s_count, c0 + c1 + c2 + c3);
        base = __shfl(base, 0);

        const unsigned long long below = (lane == 63)
            ? 0xFFFFFFFFFFFFFFFFull >> 1
            : ((1ull << lane) - 1);
        if (in0) s_idx[base + __popcll(m0 & below)] = n0 + 0;
        if (in1) s_idx[base + c0 + __popcll(m1 & below)] = n0 + 1;
        if (in2) s_idx[base + c0 + c1 + __popcll(m2 & below)] = n0 + 2;
        if (in3) s_idx[base + c0 + c1 + c2 + __popcll(m3 & below)] = n0 + 3;
    }
    __syncthreads();
    const int count = s_count;

    // pad so the gather always runs full 8-deep batches (dupes harmless)
    if (count > 0 && tid < PAD1) s_idx[count + tid] = s_idx[0];
    __syncthreads();

    // ---- phase 2: gather-max. wave w owns list slots w, w+4, ...; lane l
    // covers channels [4l,4l+4) -> one full 1KB row per wave-instruction ----
    const float* fb = feats + (size_t)b * Nn * Cn;
    float4 mx = make_float4(-INFINITY, -INFINITY, -INFINITY, -INFINITY);
    for (int i = w; i < count; i += 8 * W1T) {
        const int a0 = s_idx[i + 0 * W1T], a1 = s_idx[i + 1 * W1T];
        const int a2 = s_idx[i + 2 * W1T], a3 = s_idx[i + 3 * W1T];
        const int a4 = s_idx[i + 4 * W1T], a5 = s_idx[i + 5 * W1T];
        const int a6 = s_idx[i + 6 * W1T], a7 = s_idx[i + 7 * W1T];
        const float4 f0 = *(const float4*)(fb + (size_t)a0 * Cn + lane * 4);
        const float4 f1 = *(const float4*)(fb + (size_t)a1 * Cn + lane * 4);
        const float4 f2 = *(const float4*)(fb + (size_t)a2 * Cn + lane * 4);
        const float4 f3 = *(const float4*)(fb + (size_t)a3 * Cn + lane * 4);
        const float4 f4 = *(const float4*)(fb + (size_t)a4 * Cn + lane * 4);
        const float4 f5 = *(const float4*)(fb + (size_t)a5 * Cn + lane * 4);
        const float4 f6 = *(const float4*)(fb + (size_t)a6 * Cn + lane * 4);
        const float4 f7 = *(const float4*)(fb + (size_t)a7 * Cn + lane * 4);
        mx = max4(mx, max4(max4(f0, f1), max4(f2, f3)));
        mx = max4(mx, max4(max4(f4, f5), max4(f6, f7)));
    }
    *(float4*)&s_part[w][lane * 4] = mx;
    __syncthreads();

    // ---- phase 3: reduce 4 wave-partials, publish (keep -inf sentinel) ----
    {
        const float m = fmaxf(fmaxf(s_part[0][tid], s_part[1][tid]),
                              fmaxf(s_part[2][tid], s_part[3][tid]));
        partial[(size_t)blk * Cn + tid] = m;
    }
    // device-scope release, then per-box ticket
    __threadfence();
    if (tid == 0) s_done = (int)atomicAdd(&counters[bk], 1u);
    __syncthreads();
    if (s_done != NSEG - 1) return;        // not the last block of this box

    // ---- phase 4 (last block of box bk only): acquire + reduce 8 + MLP ----
    __threadfence();
    {
        const float* pp = partial + (size_t)bk * NSEG * Cn + tid;
        float m = pp[0];
        #pragma unroll
        for (int j = 1; j < NSEG; ++j) m = fmaxf(m, pp[(size_t)j * Cn]);
        if (m == -INFINITY) m = 0.0f;      // empty box -> 0
        s_vec[tid] = m;
    }
    __syncthreads();

    // layer 1: thread d owns neuron d; chain-256 fmaf, coalesced W reads
    {
        float acc = b1[tid];
        #pragma unroll 16
        for (int c = 0; c < Cn; ++c)
            acc = fmaf(s_vec[c], W1[(size_t)c * 256 + tid], acc);
        s_h[tid] = fmaxf(acc, 0.0f);
    }
    __syncthreads();

    // layer 2
    {
        float acc = b2[tid];
        #pragma unroll 16
        for (int c = 0; c < Cn; ++c)
            acc = fmaf(s_h[c], W2[(size_t)c * 256 + tid], acc);
        out[(size_t)bk * 256 + tid] = fmaxf(acc, 0.0f);
    }
}

extern "C" void kernel_launch(void* const* d_in, const int* in_sizes, int n_in,
                              void* d_out, int out_size, void* d_ws, size_t ws_size,
                              hipStream_t stream) {
    const float* points    = (const float*)d_in[0];
    const float* feats     = (const float*)d_in[1];
    const float* proposals = (const float*)d_in[2];
    const float* W1        = (const float*)d_in[3];
    const float* b1        = (const float*)d_in[4];
    const float* W2        = (const float*)d_in[5];
    const float* b2        = (const float*)d_in[6];
    float* out             = (float*)d_out;

    float*    partial  = (float*)d_ws;                       // 1 MB
    unsigned* counters = (unsigned*)((char*)d_ws + (size_t)NB1 * Cn * 4);

    // zero the 128 per-box tickets (ws is poisoned every iteration)
    hipMemsetAsync(counters, 0, BK * sizeof(unsigned), stream);

    pool_seg_mlp_kernel<<<NB1, 256, 0, stream>>>(points, feats, proposals,
                                                 W1, b1, W2, b2, out,
                                                 partial, counters);
}

// Round 9
// 79.890 us; speedup vs baseline: 2.2052x; 2.2052x over previous
//
#include <hip/hip_runtime.h>

#define Bn 2
#define Nn 4096
#define Cn 256
#define Kn 64
#define BK (Bn * Kn)
#define NSEG 8                 // eighths of N per box
#define SEGN (Nn / NSEG)       // 512 points per k1 block
#define NB1 (BK * NSEG)        // 1024 k1 blocks
#define W1T 4                  // waves per k1 block
#define PAD1 (7 * W1T)         // gather batch over-read padding

__device__ __forceinline__ float4 max4(float4 a, float4 b) {
    return make_float4(fmaxf(a.x, b.x), fmaxf(a.y, b.y),
                       fmaxf(a.z, b.z), fmaxf(a.w, b.w));
}

// ---------------- Kernel 1: (box, eighth) -> 256-float pooled partial -----
// 1024 small blocks (256 thr, ~6 KB LDS) -> 4 blocks/CU: four independent
// scan->gather phase-chains per CU so cold-HBM gather latency of one block
// overlaps scan/compact/reduce of the others.
__global__ __launch_bounds__(256) void pool_seg_kernel(
    const float* __restrict__ points,      // (B,N,3)
    const float* __restrict__ feats,       // (B,N,C)
    const float* __restrict__ proposals,   // (B,K,7)
    float* __restrict__ partial)           // (NB1, 256): -inf when empty
{
    const int blk  = blockIdx.x;
    const int bk   = blk >> 3;             // box 0..127
    const int seg  = blk & 7;              // eighth 0..7
    const int b    = bk / Kn;
    const int tid  = threadIdx.x;
    const int w    = tid >> 6;             // wave 0..3
    const int lane = tid & 63;

    __shared__ int   s_idx[SEGN + PAD1];   // 2.2 KB
    __shared__ int   s_count;
    __shared__ float s_part[W1T][Cn];      // 4 KB

    // ---- box bounds ----
    const float* prop = proposals + (size_t)bk * 7;
    const float cx = prop[0], cy = prop[1], cz = prop[2];
    const float hx = prop[3] * 0.5f, hy = prop[4] * 0.5f, hz = prop[5] * 0.5f;
    const float lox = cx - hx, loy = cy - hy, loz = cz - hz;
    const float hix = cx + hx, hiy = cy + hy, hiz = cz + hz;

    if (tid == 0) s_count = 0;
    __syncthreads();

    // ---- phase 1: scan this eighth's 512 points. Threads 0..127 own 4
    // points each via 3 float4 loads; wave-aggregated ballot compaction.
    if (tid < 128) {
        const int n0 = seg * SEGN + 4 * tid;
        const float4* pv = (const float4*)(points + (size_t)b * Nn * 3
                                           + (size_t)seg * SEGN * 3);
        const float4 q0 = pv[3 * tid + 0];   // x0 y0 z0 x1
        const float4 q1 = pv[3 * tid + 1];   // y1 z1 x2 y2
        const float4 q2 = pv[3 * tid + 2];   // z2 x3 y3 z3

        const bool in0 = (q0.x > lox) & (q0.x < hix) &
                         (q0.y > loy) & (q0.y < hiy) &
                         (q0.z > loz) & (q0.z < hiz);
        const bool in1 = (q0.w > lox) & (q0.w < hix) &
                         (q1.x > loy) & (q1.x < hiy) &
                         (q1.y > loz) & (q1.y < hiz);
        const bool in2 = (q1.z > lox) & (q1.z < hix) &
                         (q1.w > loy) & (q1.w < hiy) &
                         (q2.x > loz) & (q2.x < hiz);
        const bool in3 = (q2.y > lox) & (q2.y < hix) &
                         (q2.z > loy) & (q2.z < hiy) &
                         (q2.w > loz) & (q2.w < hiz);

        const unsigned long long m0 = __ballot(in0);
        const unsigned long long m1 = __ballot(in1);
        const unsigned long long m2 = __ballot(in2);
        const unsigned long long m3 = __ballot(in3);
        const int c0 = __popcll(m0), c1 = __popcll(m1);
        const int c2 = __popcll(m2), c3 = __popcll(m3);

        int base = 0;
        if (lane == 0) base = atomicAdd(&s_count, c0 + c1 + c2 + c3);
        base = __shfl(base, 0);

        const unsigned long long below = (lane == 63)
            ? 0xFFFFFFFFFFFFFFFFull >> 1
            : ((1ull << lane) - 1);
        if (in0) s_idx[base + __popcll(m0 & below)] = n0 + 0;
        if (in1) s_idx[base + c0 + __popcll(m1 & below)] = n0 + 1;
        if (in2) s_idx[base + c0 + c1 + __popcll(m2 & below)] = n0 + 2;
        if (in3) s_idx[base + c0 + c1 + c2 + __popcll(m3 & below)] = n0 + 3;
    }
    __syncthreads();
    const int count = s_count;

    // pad so the gather always runs full 8-deep batches (dupes harmless)
    if (count > 0 && tid < PAD1) s_idx[count + tid] = s_idx[0];
    __syncthreads();

    // ---- phase 2: gather-max. wave w owns list slots w, w+4, ...; lane l
    // covers channels [4l,4l+4) -> one full 1KB row per wave-instruction ----
    const float* fb = feats + (size_t)b * Nn * Cn;
    float4 mx = make_float4(-INFINITY, -INFINITY, -INFINITY, -INFINITY);
    for (int i = w; i < count; i += 8 * W1T) {
        const int a0 = s_idx[i + 0 * W1T], a1 = s_idx[i + 1 * W1T];
        const int a2 = s_idx[i + 2 * W1T], a3 = s_idx[i + 3 * W1T];
        const int a4 = s_idx[i + 4 * W1T], a5 = s_idx[i + 5 * W1T];
        const int a6 = s_idx[i + 6 * W1T], a7 = s_idx[i + 7 * W1T];
        const float4 f0 = *(const float4*)(fb + (size_t)a0 * Cn + lane * 4);
        const float4 f1 = *(const float4*)(fb + (size_t)a1 * Cn + lane * 4);
        const float4 f2 = *(const float4*)(fb + (size_t)a2 * Cn + lane * 4);
        const float4 f3 = *(const float4*)(fb + (size_t)a3 * Cn + lane * 4);
        const float4 f4 = *(const float4*)(fb + (size_t)a4 * Cn + lane * 4);
        const float4 f5 = *(const float4*)(fb + (size_t)a5 * Cn + lane * 4);
        const float4 f6 = *(const float4*)(fb + (size_t)a6 * Cn + lane * 4);
        const float4 f7 = *(const float4*)(fb + (size_t)a7 * Cn + lane * 4);
        mx = max4(mx, max4(max4(f0, f1), max4(f2, f3)));
        mx = max4(mx, max4(max4(f4, f5), max4(f6, f7)));
    }
    *(float4*)&s_part[w][lane * 4] = mx;
    __syncthreads();

    // ---- phase 3: reduce 4 wave-partials, write (keep -inf sentinel) ----
    // 256 threads cover the 256 channels exactly.
    {
        float m = fmaxf(fmaxf(s_part[0][tid], s_part[1][tid]),
                        fmaxf(s_part[2][tid], s_part[3][tid]));
        partial[(size_t)blk * Cn + tid] = m;
    }
}

// ---------------- Kernel 2: combine 8 partials + 2-layer MLP --------------
// grid = 128 blocks x 1024 thr, proven c-split-4 MLP (R2 structure).
__global__ __launch_bounds__(1024) void reduce_mlp_kernel(
    const float* __restrict__ partial,     // (NB1, 256)
    const float* __restrict__ W1,          // (C,256)
    const float* __restrict__ b1,
    const float* __restrict__ W2,          // (256,256)
    const float* __restrict__ b2,
    float* __restrict__ out)               // (B,K,256)
{
    const int bk  = blockIdx.x;
    const int tid = threadIdx.x;
    const int g   = tid >> 8;              // 0..3
    const int d   = tid & 255;

    __shared__ float s_m[4][Cn];
    __shared__ float s_vec[Cn];
    __shared__ float s_red[4][Cn];

    // each group reduces 2 of the box's 8 partials
    {
        const float* pp = partial + ((size_t)bk * NSEG) * Cn + d;
        const float a = pp[(size_t)(2 * g + 0) * Cn];
        const float c = pp[(size_t)(2 * g + 1) * Cn];
        s_m[g][d] = fmaxf(a, c);
    }
    __syncthreads();

    if (tid < Cn) {
        float m = fmaxf(fmaxf(s_m[0][tid], s_m[1][tid]),
                        fmaxf(s_m[2][tid], s_m[3][tid]));
        if (m == -INFINITY) m = 0.0f;      // empty box -> 0
        s_vec[tid] = m;
    }
    __syncthreads();

    // layer 1, c-split 4 ways (chain length 64)
    {
        const float* w1 = W1 + (size_t)(g * 64) * 256 + d;
        const float* sv = s_vec + g * 64;
        float acc = 0.0f;
        #pragma unroll 16
        for (int c = 0; c < 64; ++c)
            acc = fmaf(sv[c], w1[(size_t)c * 256], acc);
        s_red[g][d] = acc;
    }
    __syncthreads();
    if (tid < Cn) {
        s_vec[tid] = fmaxf(
            b1[tid] + ((s_red[0][tid] + s_red[1][tid]) +
                       (s_red[2][tid] + s_red[3][tid])), 0.0f);
    }
    __syncthreads();

    // layer 2
    {
        const float* w2 = W2 + (size_t)(g * 64) * 256 + d;
        const float* sv = s_vec + g * 64;
        float acc = 0.0f;
        #pragma unroll 16
        for (int c = 0; c < 64; ++c)
            acc = fmaf(sv[c], w2[(size_t)c * 256], acc);
        s_red[g][d] = acc;
    }
    __syncthreads();
    if (tid < Cn) {
        out[(size_t)bk * 256 + tid] = fmaxf(
            b2[tid] + ((s_red[0][tid] + s_red[1][tid]) +
                       (s_red[2][tid] + s_red[3][tid])), 0.0f);
    }
}

extern "C" void kernel_launch(void* const* d_in, const int* in_sizes, int n_in,
                              void* d_out, int out_size, void* d_ws, size_t ws_size,
                              hipStream_t stream) {
    const float* points    = (const float*)d_in[0];
    const float* feats     = (const float*)d_in[1];
    const float* proposals = (const float*)d_in[2];
    const float* W1        = (const float*)d_in[3];
    const float* b1        = (const float*)d_in[4];
    const float* W2        = (const float*)d_in[5];
    const float* b2        = (const float*)d_in[6];
    float* out             = (float*)d_out;
    float* partial         = (float*)d_ws;         // 1024*256*4 = 1 MB

    pool_seg_kernel<<<NB1, 256, 0, stream>>>(points, feats, proposals,
                                             partial);
    reduce_mlp_kernel<<<BK, 1024, 0, stream>>>(partial, W1, b1, W2, b2, out);
}